// Round 3
// baseline (9669.445 us; speedup 1.0000x reference)
//
#include <hip/hip_runtime.h>

#define TS 512
#define NB 64
#define FIN 512
#define HD 512

typedef short bf16x8 __attribute__((ext_vector_type(8)));
typedef float f32x4 __attribute__((ext_vector_type(4)));

__device__ __forceinline__ unsigned short f2bf(float f) {
  union { float f; unsigned int i; } v; v.f = f;
  unsigned int r = v.i + 0x7fffu + ((v.i >> 16) & 1u);  // RNE
  return (unsigned short)(r >> 16);
}
__device__ __forceinline__ bf16x8 pack8(const float* __restrict__ p) {
  bf16x8 r;
#pragma unroll
  for (int i = 0; i < 8; ++i) r[i] = (short)f2bf(p[i]);
  return r;
}
__device__ __forceinline__ float sigm(float x) { return 1.0f / (1.0f + __expf(-x)); }
__device__ __forceinline__ float tanh_(float x) { return 1.0f - 2.0f / (__expf(2.0f * x) + 1.0f); }

// Persistent fused LSTM. fp32 inputs, fp32 outputs (h and c), bf16 internal MFMA.
// Grid: 256 WGs = 4 batch groups (bg) x 64 hidden groups (hg).
// WG(bg,hg): batches [bg*16, bg*16+16), hidden [hg*8, hg*8+8) -> 32 gate rows.
// Waves 0,1: x @ W_ih^T (K halves 0/1). Waves 2,3: h @ W_hh^T (K halves 0/1).
// Weights held as bf16 fragments in registers for all 512 steps.
// Sync: per-bg flag array; flag[hg] = number of steps WG(bg,hg) published.
__global__ void __launch_bounds__(256, 1) lstm_persist(
    const float* __restrict__ seq,
    const float* __restrict__ w_ih,
    const float* __restrict__ w_hh,
    const float* __restrict__ b_ih,
    const float* __restrict__ b_hh,
    float* __restrict__ out,
    unsigned short* __restrict__ hbuf,   // [2][NB][HD] bf16 in d_ws
    int* __restrict__ flags)             // [4][64] in d_ws
{
  const int wg   = blockIdx.x;
  const int hg   = wg & 63;
  const int bg   = wg >> 6;
  const int tid  = threadIdx.x;
  const int lane = tid & 63;
  const int wave = tid >> 6;
  const int mb0  = bg * 16;
  const int hid0 = hg * 8;
  const int nloc = lane & 15;   // A: m (batch). B: n (gate col). C/D: col = n.
  const int quad = lane >> 4;   // A/B: k-chunk. C/D: row block (m).

  __shared__ __align__(16) float gred[4][32][20];  // [wave][n 0..31][m 0..15 +pad]

  const float* W = (wave < 2) ? w_ih : w_hh;
  const int k0 = (wave & 1) * 256;  // this wave's K half

  // ---- convert step-invariant weight fragments into bf16 registers ----
  // gate row order n = gtype*8 + j  ->  global row gtype*512 + hid0 + j
  bf16x8 bfrag[2][8];  // [ntile][kiter]
#pragma unroll
  for (int nt = 0; nt < 2; ++nt) {
    int n = nt * 16 + nloc;
    int grow = (n >> 3) * HD + hid0 + (n & 7);
    const float* src = W + (size_t)grow * FIN + k0 + quad * 8;
#pragma unroll
    for (int kk = 0; kk < 8; ++kk) {
      float tmp[8];
      *(f32x4*)&tmp[0] = *(const f32x4*)(src + kk * 32);
      *(f32x4*)&tmp[4] = *(const f32x4*)(src + kk * 32 + 4);
      bfrag[nt][kk] = pack8(tmp);
    }
  }

  // ---- cell-thread state (threads 0..127: one (batch,hid) each) ----
  float bias_[4] = {0.f, 0.f, 0.f, 0.f};
  float cprev = 0.0f;
  int cb = 0, cj = 0;
  if (tid < 128) {
    cb = tid >> 3;   // local batch 0..15
    cj = tid & 7;    // local hid 0..7
#pragma unroll
    for (int g = 0; g < 4; ++g) {
      int r = g * HD + hid0 + cj;
      bias_[g] = b_ih[r] + b_hh[r];
    }
  }

  const size_t ax_base = (size_t)(mb0 + nloc) * FIN + k0 + quad * 8;
  const size_t ah_base = (size_t)(mb0 + nloc) * HD  + k0 + quad * 8;
  int* dom_flag = flags + bg * 64 + lane;  // each lane polls one peer
  int* my_flag  = flags + bg * 64 + hg;

  for (int t = 0; t < TS; ++t) {
    f32x4 acc0 = {0.f, 0.f, 0.f, 0.f};
    f32x4 acc1 = {0.f, 0.f, 0.f, 0.f};

    if (wave < 2) {
      // x-projection: no cross-WG dependency; overlaps peers' h wait
      const float* ap = seq + (size_t)t * (NB * FIN) + ax_base;
      bf16x8 afr[8];
#pragma unroll
      for (int kk = 0; kk < 8; ++kk) {
        float tmp[8];
        *(f32x4*)&tmp[0] = *(const f32x4*)(ap + kk * 32);
        *(f32x4*)&tmp[4] = *(const f32x4*)(ap + kk * 32 + 4);
        afr[kk] = pack8(tmp);
      }
#pragma unroll
      for (int kk = 0; kk < 8; ++kk) {
        acc0 = __builtin_amdgcn_mfma_f32_16x16x32_bf16(afr[kk], bfrag[0][kk], acc0, 0, 0, 0);
        acc1 = __builtin_amdgcn_mfma_f32_16x16x32_bf16(afr[kk], bfrag[1][kk], acc1, 0, 0, 0);
      }
    } else if (t > 0) {
      // wait for h_{t-1} from all 64 WGs of this batch group
      for (int spin = 0; spin < (1 << 22); ++spin) {  // bailout guards vs hang
        int v = __hip_atomic_load(dom_flag, __ATOMIC_RELAXED, __HIP_MEMORY_SCOPE_AGENT);
        if (!__any(v < t)) break;   // flag >= t  <=>  h_{t-1} published
      }
      __threadfence();  // acquire: invalidate stale L1/L2 lines before hbuf reads
      const unsigned short* ap = hbuf + (size_t)((t - 1) & 1) * (NB * HD) + ah_base;
      bf16x8 afr[8];
#pragma unroll
      for (int kk = 0; kk < 8; ++kk) afr[kk] = *(const bf16x8*)(ap + kk * 32);
#pragma unroll
      for (int kk = 0; kk < 8; ++kk) {
        acc0 = __builtin_amdgcn_mfma_f32_16x16x32_bf16(afr[kk], bfrag[0][kk], acc0, 0, 0, 0);
        acc1 = __builtin_amdgcn_mfma_f32_16x16x32_bf16(afr[kk], bfrag[1][kk], acc1, 0, 0, 0);
      }
    }
    // C/D layout: col = lane&15 (= n), row m = quad*4 + reg
    *(f32x4*)&gred[wave][nloc][quad * 4]      = acc0;
    *(f32x4*)&gred[wave][16 + nloc][quad * 4] = acc1;
    __syncthreads();

    if (tid < 128) {
      float gs[4];
#pragma unroll
      for (int g = 0; g < 4; ++g) {
        int n = g * 8 + cj;
        gs[g] = bias_[g] + gred[0][n][cb] + gred[1][n][cb] + gred[2][n][cb] + gred[3][n][cb];
      }
      float ig = sigm(gs[0]);
      float fg = sigm(gs[1]);
      float gg = tanh_(gs[2]);
      float og = sigm(gs[3]);
      float c  = fg * cprev + ig * gg;
      cprev = c;
      float h  = og * tanh_(c);
      size_t o = (size_t)t * (NB * HD) + (size_t)(mb0 + cb) * HD + hid0 + cj;
      out[o] = h;
      out[(size_t)TS * NB * HD + o] = c;
      hbuf[(size_t)(t & 1) * (NB * HD) + (size_t)(mb0 + cb) * HD + hid0 + cj] = f2bf(h);
    }
    __syncthreads();  // drains each wave's vmcnt before barrier -> h stores in L2
    if (tid == 0)
      __hip_atomic_store(my_flag, t + 1, __ATOMIC_RELEASE, __HIP_MEMORY_SCOPE_AGENT);
  }
}

extern "C" void kernel_launch(void* const* d_in, const int* in_sizes, int n_in,
                              void* d_out, int out_size, void* d_ws, size_t ws_size,
                              hipStream_t stream) {
  const float* seq = (const float*)d_in[0];
  const float* wih = (const float*)d_in[1];
  const float* whh = (const float*)d_in[2];
  const float* bih = (const float*)d_in[3];
  const float* bhh = (const float*)d_in[4];
  float* out = (float*)d_out;
  unsigned short* hbuf = (unsigned short*)d_ws;                      // 2*64*512*2 B = 128 KiB
  int* flags           = (int*)((char*)d_ws + 2 * NB * HD * 2);      // 4*64*4 B
  hipLaunchKernelGGL(lstm_persist, dim3(256), dim3(256), 0, stream,
                     seq, wih, whh, bih, bhh, out, hbuf, flags);
}

// Round 4
// 3978.981 us; speedup vs baseline: 2.4301x; 2.4301x over previous
//
#include <hip/hip_runtime.h>

#define TS 512
#define NB 64
#define FIN 512
#define HD 512
#define HBUF_U64 (NB * HD / 2)   // 16384 u64 per buffer; 4 buffers = 512 KiB in d_ws

typedef short bf16x8 __attribute__((ext_vector_type(8)));
typedef float f32x4 __attribute__((ext_vector_type(4)));

__device__ __forceinline__ unsigned short f2bf(float f) {
  union { float f; unsigned int i; } v; v.f = f;
  unsigned int r = v.i + 0x7fffu + ((v.i >> 16) & 1u);  // RNE
  return (unsigned short)(r >> 16);
}
__device__ __forceinline__ bf16x8 packv(f32x4 a, f32x4 b) {
  bf16x8 r;
#pragma unroll
  for (int i = 0; i < 4; ++i) r[i] = (short)f2bf(a[i]);
#pragma unroll
  for (int i = 0; i < 4; ++i) r[4 + i] = (short)f2bf(b[i]);
  return r;
}
__device__ __forceinline__ float sigm(float x) { return 1.0f / (1.0f + __expf(-x)); }
__device__ __forceinline__ float tanh_(float x) { return 1.0f - 2.0f / (__expf(2.0f * x) + 1.0f); }

// Persistent fused LSTM. fp32 in, fp32 out, bf16 MFMA internal.
// Grid: 256 WGs = 4 batch groups (bg) x 64 hidden groups (hg).
// WG(bg,hg): batches [bg*16,+16), hidden [hg*8,+8) -> 32 gate rows.
// Waves 0,1: x @ W_ih^T (K halves). Waves 2,3: h @ W_hh^T (K halves).
// Weights as bf16 fragments in registers for all 512 steps.
// h exchange: tagged u64 {tag=t+1 | 2xbf16} via RELAXED agent atomics (write-
// through IF, point-coherent) -> NO wbl2/inv cache maintenance, no flags,
// no release fences. 4 rotating buffers make overwrite provably safe.
__global__ void __launch_bounds__(256, 1) lstm_persist(
    const float* __restrict__ seq,
    const float* __restrict__ w_ih,
    const float* __restrict__ w_hh,
    const float* __restrict__ b_ih,
    const float* __restrict__ b_hh,
    float* __restrict__ out,
    unsigned long long* __restrict__ hbuf)  // [4][NB*HD/2] tagged u64 in d_ws
{
  const int wg   = blockIdx.x;
  const int hg   = wg & 63;
  const int bg   = wg >> 6;
  const int tid  = threadIdx.x;
  const int wave = tid >> 6;
  const int lane = tid & 63;
  const int mb0  = bg * 16;
  const int hid0 = hg * 8;
  const int nloc = lane & 15;   // A: m (batch). B: n (gate col). C/D: col = n.
  const int quad = lane >> 4;   // A/B: k-chunk. C/D: row block (m).

  __shared__ __align__(16) float gred[2][4][32][20];  // [t&1][wave][n][m +pad]

  const float* W = (wave < 2) ? w_ih : w_hh;
  const int k0 = (wave & 1) * 256;  // this wave's K half

  // ---- step-invariant weight fragments -> bf16 registers ----
  bf16x8 bfrag[2][8];  // [ntile][kiter]
#pragma unroll
  for (int nt = 0; nt < 2; ++nt) {
    int n = nt * 16 + nloc;
    int grow = (n >> 3) * HD + hid0 + (n & 7);  // gate row: gtype*512 + hid0 + j
    const float* src = W + (size_t)grow * FIN + k0 + quad * 8;
#pragma unroll
    for (int kk = 0; kk < 8; ++kk)
      bfrag[nt][kk] = packv(*(const f32x4*)(src + kk * 32),
                            *(const f32x4*)(src + kk * 32 + 4));
  }

  // ---- cell-thread state (threads 0..127: one (batch,hid) each) ----
  float bias_[4] = {0.f, 0.f, 0.f, 0.f};
  float cprev = 0.0f;
  int cb = 0, cj = 0;
  if (tid < 128) {
    cb = tid >> 3;   // local batch 0..15
    cj = tid & 7;    // local hid 0..7
#pragma unroll
    for (int g = 0; g < 4; ++g) {
      int r = g * HD + hid0 + cj;
      bias_[g] = b_ih[r] + b_hh[r];
    }
  }

  const size_t ax_base = (size_t)(mb0 + nloc) * FIN + k0 + quad * 8;
  const int hrow_u64 = ((mb0 + nloc) * HD + k0) >> 1;  // reader base in u64 units

  // ---- software-prefetch x(0) into registers (waves 0,1) ----
  f32x4 xpf[16];
  if (wave < 2) {
    const float* ap = seq + ax_base;
#pragma unroll
    for (int kk = 0; kk < 8; ++kk) {
      xpf[2 * kk]     = *(const f32x4*)(ap + kk * 32);
      xpf[2 * kk + 1] = *(const f32x4*)(ap + kk * 32 + 4);
    }
  }

  for (int t = 0; t < TS; ++t) {
    f32x4 acc0 = {0.f, 0.f, 0.f, 0.f};
    f32x4 acc1 = {0.f, 0.f, 0.f, 0.f};

    if (wave < 2) {
      // x-projection from prefetched regs; no cross-WG dependency
      bf16x8 afr[8];
#pragma unroll
      for (int kk = 0; kk < 8; ++kk) afr[kk] = packv(xpf[2 * kk], xpf[2 * kk + 1]);
#pragma unroll
      for (int kk = 0; kk < 8; ++kk) {
        acc0 = __builtin_amdgcn_mfma_f32_16x16x32_bf16(afr[kk], bfrag[0][kk], acc0, 0, 0, 0);
        acc1 = __builtin_amdgcn_mfma_f32_16x16x32_bf16(afr[kk], bfrag[1][kk], acc1, 0, 0, 0);
      }
      // prefetch x(t+1) (lands during the rest of this step)
      int tn = (t + 1 < TS) ? t + 1 : TS - 1;
      const float* ap = seq + (size_t)tn * (NB * FIN) + ax_base;
#pragma unroll
      for (int kk = 0; kk < 8; ++kk) {
        xpf[2 * kk]     = *(const f32x4*)(ap + kk * 32);
        xpf[2 * kk + 1] = *(const f32x4*)(ap + kk * 32 + 4);
      }
    } else if (t > 0) {
      // gather tagged h(t-1): 32 u64 loads, re-load stale until tag >= t
      const unsigned long long* hb =
          hbuf + (size_t)((t - 1) & 3) * HBUF_U64 + hrow_u64;
      unsigned long long hv[32];
      unsigned int done = 0;
      for (int r = 0; r < 8192; ++r) {
#pragma unroll
        for (int i = 0; i < 32; ++i)
          if (!((done >> i) & 1u))
            hv[i] = __hip_atomic_load(hb + ((i >> 2) * 16 + quad * 4 + (i & 3)),
                                      __ATOMIC_RELAXED, __HIP_MEMORY_SCOPE_AGENT);
        unsigned int nd = done;
#pragma unroll
        for (int i = 0; i < 32; ++i)
          if (!((nd >> i) & 1u) && (int)(unsigned int)(hv[i] >> 32) >= t)
            nd |= 1u << i;
        done = nd;
        if (done == 0xffffffffu) break;
        __builtin_amdgcn_s_sleep(1);  // throttle IF poll traffic
      }
      bf16x8 afr[8];
#pragma unroll
      for (int kk = 0; kk < 8; ++kk) {
        union { unsigned int d[4]; bf16x8 v; } u;
#pragma unroll
        for (int j = 0; j < 4; ++j) u.d[j] = (unsigned int)hv[kk * 4 + j];
        afr[kk] = u.v;
      }
#pragma unroll
      for (int kk = 0; kk < 8; ++kk) {
        acc0 = __builtin_amdgcn_mfma_f32_16x16x32_bf16(afr[kk], bfrag[0][kk], acc0, 0, 0, 0);
        acc1 = __builtin_amdgcn_mfma_f32_16x16x32_bf16(afr[kk], bfrag[1][kk], acc1, 0, 0, 0);
      }
    }
    // C/D layout: col = lane&15 (= n), row m = quad*4 + reg
    *(f32x4*)&gred[t & 1][wave][nloc][quad * 4]      = acc0;
    *(f32x4*)&gred[t & 1][wave][16 + nloc][quad * 4] = acc1;
    __syncthreads();  // the only barrier per step (gred is double-buffered)

    if (tid < 128) {
      float gs[4];
#pragma unroll
      for (int g = 0; g < 4; ++g) {
        int n = g * 8 + cj;
        gs[g] = bias_[g] + gred[t & 1][0][n][cb] + gred[t & 1][1][n][cb] +
                gred[t & 1][2][n][cb] + gred[t & 1][3][n][cb];
      }
      float ig = sigm(gs[0]);
      float fg = sigm(gs[1]);
      float gg = tanh_(gs[2]);
      float og = sigm(gs[3]);
      float c  = fg * cprev + ig * gg;
      cprev = c;
      float h  = og * tanh_(c);
      size_t o = (size_t)t * (NB * HD) + (size_t)(mb0 + cb) * HD + hid0 + cj;
      out[o] = h;
      out[(size_t)TS * NB * HD + o] = c;
      // publish tagged h pair: even thread packs (cj, cj+1)
      unsigned int hu = (unsigned int)f2bf(h);
      unsigned int ho = __shfl_down(hu, 1);
      if ((tid & 1) == 0) {
        unsigned long long tv =
            ((unsigned long long)(unsigned int)(t + 1) << 32) |
            (unsigned long long)(hu | (ho << 16));
        int eidx = (mb0 + cb) * HD + hid0 + cj;  // cj even
        __hip_atomic_store(hbuf + (size_t)(t & 3) * HBUF_U64 + (eidx >> 1), tv,
                           __ATOMIC_RELAXED, __HIP_MEMORY_SCOPE_AGENT);
      }
    }
    // no second barrier: next step's gred writes hit buffer (t+1)&1
  }
}

extern "C" void kernel_launch(void* const* d_in, const int* in_sizes, int n_in,
                              void* d_out, int out_size, void* d_ws, size_t ws_size,
                              hipStream_t stream) {
  const float* seq = (const float*)d_in[0];
  const float* wih = (const float*)d_in[1];
  const float* whh = (const float*)d_in[2];
  const float* bih = (const float*)d_in[3];
  const float* bhh = (const float*)d_in[4];
  float* out = (float*)d_out;
  unsigned long long* hbuf = (unsigned long long*)d_ws;  // 4*16384*8 = 512 KiB
  hipLaunchKernelGGL(lstm_persist, dim3(256), dim3(256), 0, stream,
                     seq, wih, whh, bih, bhh, out, hbuf);
}